// Round 10
// baseline (487.770 us; speedup 1.0000x reference)
//
#include <hip/hip_runtime.h>
#include <math.h>

#define N_NODES 100000
#define N_EDGES 600000
#define HIDDEN 128
#define EDGE_CH 4
#define NUM_LAYERS 3
#define MLP_ROWS 64   // nodes per block in fp32 fallback mlp_kernel

#define SCAN_BLOCK 256
#define SCAN_GRID ((N_NODES + SCAN_BLOCK - 1) / SCAN_BLOCK)   // 391

#define HSTR 132            // padded LDS row stride (floats) for silu transpose
#define MLP3_TILES ((N_NODES + 127) / 128)   // 782
#define MLP3_GRID 256       // 1 block/CU (LDS-bound), grid-stride over tiles

typedef short bf16x8 __attribute__((ext_vector_type(8)));
typedef float f32x4  __attribute__((ext_vector_type(4)));

__device__ inline unsigned short f2bf(float x) {           // RNE fp32 -> bf16 bits
    unsigned u = __float_as_uint(x);
    return (unsigned short)((u + 0x7fff + ((u >> 16) & 1)) >> 16);
}
__device__ inline float bf2f(unsigned short b) { return __uint_as_float(((unsigned)b) << 16); }

// ---------------- common kernels ----------------

// x = emb[z] (fp32), xb = bf16 copy (fast path), agg init (atomic fallback)
__global__ void embed_init_kernel(const float* __restrict__ emb,
                                  const int* __restrict__ z,
                                  float* __restrict__ x,
                                  unsigned short* __restrict__ xb,
                                  float* __restrict__ agg,
                                  int write_agg) {
    int t = blockIdx.x * blockDim.x + threadIdx.x;
    int node = t >> 5;
    int c4 = t & 31;
    if (node < N_NODES) {
        float4 v = ((const float4*)(emb + (size_t)z[node] * HIDDEN))[c4];
        ((float4*)(x + (size_t)node * HIDDEN))[c4] = v;
        if (xb) {
            ushort4 b;
            b.x = f2bf(v.x); b.y = f2bf(v.y); b.z = f2bf(v.z); b.w = f2bf(v.w);
            ((ushort4*)(xb + (size_t)node * HIDDEN))[c4] = b;
        }
        if (write_agg)
            ((float4*)(agg + (size_t)node * HIDDEN))[c4] = v;
    }
}

// Build MFMA-fragment-ordered bf16 weight image (see round-7 comment).
__global__ void wprep_kernel(const float* __restrict__ W1, const float* __restrict__ W2,
                             unsigned short* __restrict__ wt) {
    int idx = blockIdx.x * blockDim.x + threadIdx.x;
    if (idx >= NUM_LAYERS * 2 * HIDDEN * HIDDEN) return;
    int j    = idx & 7;
    int lane = (idx >> 3) & 63;
    int ks   = (idx >> 9) & 3;
    int nt   = (idx >> 11) & 7;
    int mat  = (idx >> 14) & 1;
    int l    = idx >> 15;
    int n = nt * 16 + (lane & 15);
    int k = ks * 32 + (lane >> 4) * 8 + j;
    const float* W = mat ? W2 : W1;
    wt[idx] = f2bf(W[(size_t)l * HIDDEN * HIDDEN + (size_t)k * HIDDEN + n]);
}

// MFMA MLP v3 (+ optional bf16 shadow write for the next layer's gather).
__global__ __launch_bounds__(512, 1) void mlp_mfma3_kernel(
        const float* __restrict__ h,
        const unsigned short* __restrict__ wfrag,
        const float* __restrict__ b1, const float* __restrict__ b2,
        float* __restrict__ x, unsigned short* __restrict__ xb_out) {
    __shared__ short wlds[2 * 16384];
    __shared__ float tbuf[8 * 16 * HSTR];
    int tid   = threadIdx.x;
    int wave  = tid >> 6;
    int lane  = tid & 63;
    int row16 = lane & 15;
    int quad  = lane >> 4;
    float* myt = tbuf + wave * 16 * HSTR;

    for (int i = tid; i < 4096; i += 512)
        ((float4*)wlds)[i] = ((const float4*)wfrag)[i];
    __syncthreads();

    float bias1[8], bias2[8];
    #pragma unroll
    for (int nt = 0; nt < 8; nt++) {
        bias1[nt] = b1[nt * 16 + row16];
        bias2[nt] = b2[nt * 16 + row16];
    }

    for (int tile = blockIdx.x; tile < MLP3_TILES; tile += gridDim.x) {
        int wnode0 = tile * 128 + wave * 16;
        int mnode  = wnode0 + row16;
        bool valid = (mnode < N_NODES);
        const float* hrow = h + (size_t)(valid ? mnode : 0) * HIDDEN + quad * 8;

        bf16x8 ahi[4], alo[4];
        #pragma unroll
        for (int ks = 0; ks < 4; ks++) {
            float v[8];
            *(float4*)(v + 0) = valid ? *(const float4*)(hrow + ks * 32 + 0) : make_float4(0.f,0.f,0.f,0.f);
            *(float4*)(v + 4) = valid ? *(const float4*)(hrow + ks * 32 + 4) : make_float4(0.f,0.f,0.f,0.f);
            bf16x8 hi, lo;
            #pragma unroll
            for (int j = 0; j < 8; j++) {
                unsigned short hb = f2bf(v[j]);
                hi[j] = (short)hb;
                lo[j] = (short)f2bf(v[j] - bf2f(hb));
            }
            ahi[ks] = hi; alo[ks] = lo;
        }

        f32x4 acc[8];
        #pragma unroll
        for (int nt = 0; nt < 8; nt++) acc[nt] = (f32x4){0.f, 0.f, 0.f, 0.f};
        #pragma unroll
        for (int ks = 0; ks < 4; ks++) {
            #pragma unroll
            for (int nt = 0; nt < 8; nt++) {
                bf16x8 Bv = *(const bf16x8*)(wlds + (size_t)((nt * 4 + ks) * 64 + lane) * 8);
                acc[nt] = __builtin_amdgcn_mfma_f32_16x16x32_bf16(ahi[ks], Bv, acc[nt], 0, 0, 0);
                acc[nt] = __builtin_amdgcn_mfma_f32_16x16x32_bf16(alo[ks], Bv, acc[nt], 0, 0, 0);
            }
        }

        #pragma unroll
        for (int nt = 0; nt < 8; nt++) {
            #pragma unroll
            for (int r = 0; r < 4; r++) {
                float v = acc[nt][r] + bias1[nt];
                v = v / (1.f + __expf(-v));
                myt[(quad * 4 + r) * HSTR + nt * 16 + row16] = v;
            }
        }
        // wave-synchronous round-trip (wave-private LDS region)

        #pragma unroll
        for (int ks = 0; ks < 4; ks++) {
            const float* p = myt + row16 * HSTR + ks * 32 + quad * 8;
            float v[8];
            *(float4*)(v + 0) = *(const float4*)(p + 0);
            *(float4*)(v + 4) = *(const float4*)(p + 4);
            bf16x8 hi, lo;
            #pragma unroll
            for (int j = 0; j < 8; j++) {
                unsigned short hb = f2bf(v[j]);
                hi[j] = (short)hb;
                lo[j] = (short)f2bf(v[j] - bf2f(hb));
            }
            ahi[ks] = hi; alo[ks] = lo;
        }

        #pragma unroll
        for (int nt = 0; nt < 8; nt++) acc[nt] = (f32x4){0.f, 0.f, 0.f, 0.f};
        #pragma unroll
        for (int ks = 0; ks < 4; ks++) {
            #pragma unroll
            for (int nt = 0; nt < 8; nt++) {
                bf16x8 Bv = *(const bf16x8*)(wlds + (size_t)(16384 + ((nt * 4 + ks) * 64 + lane) * 8));
                acc[nt] = __builtin_amdgcn_mfma_f32_16x16x32_bf16(ahi[ks], Bv, acc[nt], 0, 0, 0);
                acc[nt] = __builtin_amdgcn_mfma_f32_16x16x32_bf16(alo[ks], Bv, acc[nt], 0, 0, 0);
            }
        }

        #pragma unroll
        for (int nt = 0; nt < 8; nt++) {
            #pragma unroll
            for (int r = 0; r < 4; r++) {
                int node = wnode0 + quad * 4 + r;
                if (node < N_NODES) {
                    float v = acc[nt][r] + bias2[nt];
                    x[(size_t)node * HIDDEN + nt * 16 + row16] = v;
                    if (xb_out)
                        xb_out[(size_t)node * HIDDEN + nt * 16 + row16] = f2bf(v);
                }
            }
        }
    }
}

// fp32 fallback MLP
__global__ void mlp_kernel(const float* __restrict__ h,
                           const float* __restrict__ W1, const float* __restrict__ b1,
                           const float* __restrict__ W2, const float* __restrict__ b2,
                           float* __restrict__ x) {
    __shared__ float hs[MLP_ROWS * HIDDEN];
    int rg = threadIdx.x >> 5;
    int c4 = threadIdx.x & 31;
    int node0 = blockIdx.x * MLP_ROWS;

    for (int i = threadIdx.x; i < MLP_ROWS * 32; i += 256) {
        int node = node0 + (i >> 5);
        float4 v = (node < N_NODES)
                 ? ((const float4*)(h + (size_t)node * HIDDEN))[i & 31]
                 : make_float4(0.f, 0.f, 0.f, 0.f);
        ((float4*)hs)[i] = v;
    }
    __syncthreads();

    float4 acc[8];
    {
        float4 bv = ((const float4*)b1)[c4];
        #pragma unroll
        for (int r = 0; r < 8; r++) acc[r] = bv;
    }
    const float* hbase = hs + rg * 8 * HIDDEN;

    for (int k4 = 0; k4 < HIDDEN; k4 += 4) {
        float4 w0 = ((const float4*)(W1 + (size_t)(k4 + 0) * HIDDEN))[c4];
        float4 w1 = ((const float4*)(W1 + (size_t)(k4 + 1) * HIDDEN))[c4];
        float4 w2 = ((const float4*)(W1 + (size_t)(k4 + 2) * HIDDEN))[c4];
        float4 w3 = ((const float4*)(W1 + (size_t)(k4 + 3) * HIDDEN))[c4];
        #pragma unroll
        for (int r = 0; r < 8; r++) {
            float4 hv = *(const float4*)(hbase + r * HIDDEN + k4);
            acc[r].x += hv.x*w0.x + hv.y*w1.x + hv.z*w2.x + hv.w*w3.x;
            acc[r].y += hv.x*w0.y + hv.y*w1.y + hv.z*w2.y + hv.w*w3.y;
            acc[r].z += hv.x*w0.z + hv.y*w1.z + hv.z*w2.z + hv.w*w3.z;
            acc[r].w += hv.x*w0.w + hv.y*w1.w + hv.z*w2.w + hv.w*w3.w;
        }
    }

    __syncthreads();
    #pragma unroll
    for (int r = 0; r < 8; r++) {
        float4 a = acc[r];
        a.x = a.x / (1.f + __expf(-a.x));
        a.y = a.y / (1.f + __expf(-a.y));
        a.z = a.z / (1.f + __expf(-a.z));
        a.w = a.w / (1.f + __expf(-a.w));
        *(float4*)(hs + (rg * 8 + r) * HIDDEN + c4 * 4) = a;
    }
    __syncthreads();

    {
        float4 bv = ((const float4*)b2)[c4];
        #pragma unroll
        for (int r = 0; r < 8; r++) acc[r] = bv;
    }
    for (int k4 = 0; k4 < HIDDEN; k4 += 4) {
        float4 w0 = ((const float4*)(W2 + (size_t)(k4 + 0) * HIDDEN))[c4];
        float4 w1 = ((const float4*)(W2 + (size_t)(k4 + 1) * HIDDEN))[c4];
        float4 w2 = ((const float4*)(W2 + (size_t)(k4 + 2) * HIDDEN))[c4];
        float4 w3 = ((const float4*)(W2 + (size_t)(k4 + 3) * HIDDEN))[c4];
        #pragma unroll
        for (int r = 0; r < 8; r++) {
            float4 hv = *(const float4*)(hbase + r * HIDDEN + k4);
            acc[r].x += hv.x*w0.x + hv.y*w1.x + hv.z*w2.x + hv.w*w3.x;
            acc[r].y += hv.x*w0.y + hv.y*w1.y + hv.z*w2.y + hv.w*w3.y;
            acc[r].z += hv.x*w0.z + hv.y*w1.z + hv.z*w2.z + hv.w*w3.z;
            acc[r].w += hv.x*w0.w + hv.y*w1.w + hv.z*w2.w + hv.w*w3.w;
        }
    }

    #pragma unroll
    for (int r = 0; r < 8; r++) {
        int node = node0 + rg * 8 + r;
        if (node < N_NODES)
            ((float4*)(x + (size_t)node * HIDDEN))[c4] = acc[r];
    }
}

__global__ void batch_out_kernel(const int* __restrict__ bv, float* __restrict__ out) {
    int i = blockIdx.x * blockDim.x + threadIdx.x;
    if (i < N_NODES) out[i] = (float)bv[i];
}

// ---------------- CSR build ----------------

__global__ void zero_kernel(int* __restrict__ p, int n) {
    int i = blockIdx.x * blockDim.x + threadIdx.x;
    if (i < n) p[i] = 0;
}

__global__ void hist_kernel(const int* __restrict__ dst, int* __restrict__ cnt) {
    int e = blockIdx.x * blockDim.x + threadIdx.x;
    if (e < N_EDGES) atomicAdd(&cnt[dst[e]], 1);
}

__global__ void scan_partial_kernel(const int* __restrict__ cnt, int* __restrict__ bsum) {
    __shared__ int s[SCAN_BLOCK];
    int i = blockIdx.x * SCAN_BLOCK + threadIdx.x;
    s[threadIdx.x] = (i < N_NODES) ? cnt[i] : 0;
    __syncthreads();
    for (int off = SCAN_BLOCK / 2; off > 0; off >>= 1) {
        if (threadIdx.x < off) s[threadIdx.x] += s[threadIdx.x + off];
        __syncthreads();
    }
    if (threadIdx.x == 0) bsum[blockIdx.x] = s[0];
}

__global__ void scan_base_kernel(int* __restrict__ bsum) {
    __shared__ int s[512];
    int t = threadIdx.x;
    s[t] = (t < SCAN_GRID) ? bsum[t] : 0;
    __syncthreads();
    for (int off = 1; off < 512; off <<= 1) {
        int v = (t >= off) ? s[t - off] : 0;
        __syncthreads();
        s[t] += v;
        __syncthreads();
    }
    if (t < SCAN_GRID) bsum[t] = (t > 0) ? s[t - 1] : 0;
}

__global__ void scan_final_kernel(int* __restrict__ cnt, const int* __restrict__ bsum) {
    __shared__ int s[SCAN_BLOCK];
    int i = blockIdx.x * SCAN_BLOCK + threadIdx.x;
    int v = (i < N_NODES) ? cnt[i] : 0;
    s[threadIdx.x] = v;
    __syncthreads();
    for (int off = 1; off < SCAN_BLOCK; off <<= 1) {
        int u = (threadIdx.x >= off) ? s[threadIdx.x - off] : 0;
        __syncthreads();
        s[threadIdx.x] += u;
        __syncthreads();
    }
    if (i < N_NODES) cnt[i] = bsum[blockIdx.x] + s[threadIdx.x] - v;
}

__global__ void scatter2_kernel(const int* __restrict__ dst,
                                const int* __restrict__ src,
                                const float* __restrict__ edge_attr,
                                int* __restrict__ pos,
                                int* __restrict__ ssrc,
                                float4* __restrict__ sea) {
    int e = blockIdx.x * blockDim.x + threadIdx.x;
    if (e < N_EDGES) {
        int p = atomicAdd(&pos[dst[e]], 1);
        ssrc[p] = src[e];
        sea[p] = ((const float4*)edge_attr)[e];
    }
}

// bf16-gather: x_j from 256B bf16 rows (half the random traffic); self term fp32.
// Pair-unrolled so two independent xb gathers are in flight.
__global__ void gather3_kernel(const float* __restrict__ x,
                               const unsigned short* __restrict__ xb,
                               const int* __restrict__ ssrc,
                               const float4* __restrict__ sea,
                               const int* __restrict__ pos,   // pos[i]=end; start=pos[i-1]
                               const float* __restrict__ We_l,
                               const float* __restrict__ be_l,
                               float* __restrict__ h) {
    __shared__ float sWe[EDGE_CH * HIDDEN];
    __shared__ float sbe[HIDDEN];
    for (int i = threadIdx.x; i < EDGE_CH * HIDDEN; i += blockDim.x) sWe[i] = We_l[i];
    if (threadIdx.x < HIDDEN) sbe[threadIdx.x] = be_l[threadIdx.x];
    __syncthreads();

    int t = blockIdx.x * blockDim.x + threadIdx.x;
    int node = t >> 5;
    int c4 = t & 31;
    if (node >= N_NODES) return;

    int start = (node == 0) ? 0 : pos[node - 1];
    int end = pos[node];

    float4 w0 = ((const float4*)sWe)[0 * 32 + c4];
    float4 w1 = ((const float4*)sWe)[1 * 32 + c4];
    float4 w2 = ((const float4*)sWe)[2 * 32 + c4];
    float4 w3 = ((const float4*)sWe)[3 * 32 + c4];
    float4 bb = ((const float4*)sbe)[c4];

    float4 acc = make_float4(0.f, 0.f, 0.f, 0.f);
    int j = start;
    for (; j + 2 <= end; j += 2) {
        int s0 = ssrc[j];
        int s1 = ssrc[j + 1];
        float4 ea0 = sea[j];
        float4 ea1 = sea[j + 1];
        ushort4 xb0 = ((const ushort4*)(xb + (size_t)s0 * HIDDEN))[c4];
        ushort4 xb1 = ((const ushort4*)(xb + (size_t)s1 * HIDDEN))[c4];
        float m0 = bf2f(xb0.x) + ea0.x*w0.x + ea0.y*w1.x + ea0.z*w2.x + ea0.w*w3.x + bb.x;
        float m1 = bf2f(xb0.y) + ea0.x*w0.y + ea0.y*w1.y + ea0.z*w2.y + ea0.w*w3.y + bb.y;
        float m2 = bf2f(xb0.z) + ea0.x*w0.z + ea0.y*w1.z + ea0.z*w2.z + ea0.w*w3.z + bb.z;
        float m3 = bf2f(xb0.w) + ea0.x*w0.w + ea0.y*w1.w + ea0.z*w2.w + ea0.w*w3.w + bb.w;
        acc.x += fmaxf(m0, 0.f); acc.y += fmaxf(m1, 0.f);
        acc.z += fmaxf(m2, 0.f); acc.w += fmaxf(m3, 0.f);
        m0 = bf2f(xb1.x) + ea1.x*w0.x + ea1.y*w1.x + ea1.z*w2.x + ea1.w*w3.x + bb.x;
        m1 = bf2f(xb1.y) + ea1.x*w0.y + ea1.y*w1.y + ea1.z*w2.y + ea1.w*w3.y + bb.y;
        m2 = bf2f(xb1.z) + ea1.x*w0.z + ea1.y*w1.z + ea1.z*w2.z + ea1.w*w3.z + bb.z;
        m3 = bf2f(xb1.w) + ea1.x*w0.w + ea1.y*w1.w + ea1.z*w2.w + ea1.w*w3.w + bb.w;
        acc.x += fmaxf(m0, 0.f); acc.y += fmaxf(m1, 0.f);
        acc.z += fmaxf(m2, 0.f); acc.w += fmaxf(m3, 0.f);
    }
    if (j < end) {
        int s0 = ssrc[j];
        float4 ea0 = sea[j];
        ushort4 xb0 = ((const ushort4*)(xb + (size_t)s0 * HIDDEN))[c4];
        float m0 = bf2f(xb0.x) + ea0.x*w0.x + ea0.y*w1.x + ea0.z*w2.x + ea0.w*w3.x + bb.x;
        float m1 = bf2f(xb0.y) + ea0.x*w0.y + ea0.y*w1.y + ea0.z*w2.y + ea0.w*w3.y + bb.y;
        float m2 = bf2f(xb0.z) + ea0.x*w0.z + ea0.y*w1.z + ea0.z*w2.z + ea0.w*w3.z + bb.z;
        float m3 = bf2f(xb0.w) + ea0.x*w0.w + ea0.y*w1.w + ea0.z*w2.w + ea0.w*w3.w + bb.w;
        acc.x += fmaxf(m0, 0.f); acc.y += fmaxf(m1, 0.f);
        acc.z += fmaxf(m2, 0.f); acc.w += fmaxf(m3, 0.f);
    }
    float4 xi = ((const float4*)(x + (size_t)node * HIDDEN))[c4];
    acc.x += xi.x; acc.y += xi.y; acc.z += xi.z; acc.w += xi.w;
    ((float4*)(h + (size_t)node * HIDDEN))[c4] = acc;
}

// fp32 gather fallback (round-7 path)
__global__ void gather2_kernel(const float* __restrict__ x,
                               const int* __restrict__ ssrc,
                               const float4* __restrict__ sea,
                               const int* __restrict__ pos,
                               const float* __restrict__ We_l,
                               const float* __restrict__ be_l,
                               float* __restrict__ h) {
    __shared__ float sWe[EDGE_CH * HIDDEN];
    __shared__ float sbe[HIDDEN];
    for (int i = threadIdx.x; i < EDGE_CH * HIDDEN; i += blockDim.x) sWe[i] = We_l[i];
    if (threadIdx.x < HIDDEN) sbe[threadIdx.x] = be_l[threadIdx.x];
    __syncthreads();

    int t = blockIdx.x * blockDim.x + threadIdx.x;
    int node = t >> 5;
    int c4 = t & 31;
    if (node >= N_NODES) return;

    int start = (node == 0) ? 0 : pos[node - 1];
    int end = pos[node];

    float4 w0 = ((const float4*)sWe)[0 * 32 + c4];
    float4 w1 = ((const float4*)sWe)[1 * 32 + c4];
    float4 w2 = ((const float4*)sWe)[2 * 32 + c4];
    float4 w3 = ((const float4*)sWe)[3 * 32 + c4];
    float4 bb = ((const float4*)sbe)[c4];

    float4 acc = make_float4(0.f, 0.f, 0.f, 0.f);
    for (int j = start; j < end; j++) {
        int s0 = ssrc[j];
        float4 ea0 = sea[j];
        float4 xv = ((const float4*)(x + (size_t)s0 * HIDDEN))[c4];
        float m0 = xv.x + ea0.x*w0.x + ea0.y*w1.x + ea0.z*w2.x + ea0.w*w3.x + bb.x;
        float m1 = xv.y + ea0.x*w0.y + ea0.y*w1.y + ea0.z*w2.y + ea0.w*w3.y + bb.y;
        float m2 = xv.z + ea0.x*w0.z + ea0.y*w1.z + ea0.z*w2.z + ea0.w*w3.z + bb.z;
        float m3 = xv.w + ea0.x*w0.w + ea0.y*w1.w + ea0.z*w2.w + ea0.w*w3.w + bb.w;
        acc.x += fmaxf(m0, 0.f); acc.y += fmaxf(m1, 0.f);
        acc.z += fmaxf(m2, 0.f); acc.w += fmaxf(m3, 0.f);
    }
    float4 xi = ((const float4*)(x + (size_t)node * HIDDEN))[c4];
    acc.x += xi.x; acc.y += xi.y; acc.z += xi.z; acc.w += xi.w;
    ((float4*)(h + (size_t)node * HIDDEN))[c4] = acc;
}

// ---------------- Level C fallback: atomics ----------------

__global__ void edge_kernel(const float* __restrict__ x,
                            const float* __restrict__ edge_attr,
                            const int* __restrict__ src,
                            const int* __restrict__ dst,
                            const float* __restrict__ We_l,
                            const float* __restrict__ be_l,
                            float* __restrict__ agg) {
    __shared__ float sWe[EDGE_CH * HIDDEN];
    __shared__ float sbe[HIDDEN];
    for (int i = threadIdx.x; i < EDGE_CH * HIDDEN; i += blockDim.x) sWe[i] = We_l[i];
    if (threadIdx.x < HIDDEN) sbe[threadIdx.x] = be_l[threadIdx.x];
    __syncthreads();

    int t = blockIdx.x * blockDim.x + threadIdx.x;
    int e = t >> 5;
    if (e >= N_EDGES) return;
    int c4 = t & 31;

    int s = src[e];
    int d = dst[e];
    float4 ea = ((const float4*)edge_attr)[e];
    float4 w0 = ((const float4*)sWe)[0 * 32 + c4];
    float4 w1 = ((const float4*)sWe)[1 * 32 + c4];
    float4 w2 = ((const float4*)sWe)[2 * 32 + c4];
    float4 w3 = ((const float4*)sWe)[3 * 32 + c4];
    float4 bb = ((const float4*)sbe)[c4];
    float4 xv = ((const float4*)(x + (size_t)s * HIDDEN))[c4];

    float m0 = xv.x + ea.x*w0.x + ea.y*w1.x + ea.z*w2.x + ea.w*w3.x + bb.x;
    float m1 = xv.y + ea.x*w0.y + ea.y*w1.y + ea.z*w2.y + ea.w*w3.y + bb.y;
    float m2 = xv.z + ea.x*w0.z + ea.y*w1.z + ea.z*w2.z + ea.w*w3.z + bb.z;
    float m3 = xv.w + ea.x*w0.w + ea.y*w1.w + ea.z*w2.w + ea.w*w3.w + bb.w;

    float* ap = agg + (size_t)d * HIDDEN + c4 * 4;
    atomicAdd(ap + 0, fmaxf(m0, 0.f));
    atomicAdd(ap + 1, fmaxf(m1, 0.f));
    atomicAdd(ap + 2, fmaxf(m2, 0.f));
    atomicAdd(ap + 3, fmaxf(m3, 0.f));
}

// ---------------- host ----------------

extern "C" void kernel_launch(void* const* d_in, const int* in_sizes, int n_in,
                              void* d_out, int out_size, void* d_ws, size_t ws_size,
                              hipStream_t stream) {
    const float* emb       = (const float*)d_in[0];
    const float* We        = (const float*)d_in[1];
    const float* be        = (const float*)d_in[2];
    const float* W1        = (const float*)d_in[3];
    const float* b1        = (const float*)d_in[4];
    const float* W2        = (const float*)d_in[5];
    const float* b2        = (const float*)d_in[6];
    const float* edge_attr = (const float*)d_in[7];
    const int*   z         = (const int*)d_in[8];
    const int*   ei        = (const int*)d_in[9];
    const int*   bv        = (const int*)d_in[10];

    float* x   = (float*)d_out;
    float* agg = (float*)d_ws;
    const int* src = ei;
    const int* dst = ei + N_EDGES;

    const size_t AGG_BYTES  = (size_t)N_NODES * HIDDEN * sizeof(float);     // 51.2 MB
    const size_t POS_BYTES  = (size_t)N_NODES * sizeof(int);                // 0.4 MB
    const size_t SRC_BYTES  = (size_t)N_EDGES * sizeof(int);                // 2.4 MB
    const size_t EA_BYTES   = (size_t)N_EDGES * 4 * sizeof(float);          // 9.6 MB
    const size_t BSUM_BYTES = ((size_t)SCAN_GRID * sizeof(int) + 15) & ~15; // 1568 B
    const size_t WT_ELEMS   = (size_t)NUM_LAYERS * 2 * HIDDEN * HIDDEN;     // 98304
    const size_t WT_BYTES   = WT_ELEMS * sizeof(unsigned short);            // 196608 B
    const size_t XB_BYTES   = (size_t)N_NODES * HIDDEN * sizeof(unsigned short); // 25.6 MB

    const size_t OFF_POS  = AGG_BYTES;
    const size_t OFF_SRC  = OFF_POS + POS_BYTES;
    const size_t OFF_EA   = OFF_SRC + SRC_BYTES;
    const size_t OFF_BSUM = OFF_EA + EA_BYTES;
    const size_t OFF_WT   = OFF_BSUM + BSUM_BYTES;
    const size_t OFF_XB   = OFF_WT + WT_BYTES;
    const size_t TOTAL_MFMA = OFF_XB;                 // through WT
    const size_t TOTAL_XB   = OFF_XB + XB_BYTES;

    const int MLP_GRID = (N_NODES + MLP_ROWS - 1) / MLP_ROWS;

    if (ws_size >= OFF_BSUM + BSUM_BYTES) {
        int*    pos  = (int*)((char*)d_ws + OFF_POS);
        int*    ssrc = (int*)((char*)d_ws + OFF_SRC);
        float4* sea  = (float4*)((char*)d_ws + OFF_EA);
        int*    bsum = (int*)((char*)d_ws + OFF_BSUM);
        const bool mfma   = (ws_size >= TOTAL_MFMA);
        const bool use_xb = (ws_size >= TOTAL_XB) && mfma;
        unsigned short* wt = (unsigned short*)((char*)d_ws + OFF_WT);
        unsigned short* xb = (unsigned short*)((char*)d_ws + OFF_XB);

        embed_init_kernel<<<(N_NODES * 32) / 256, 256, 0, stream>>>(
            emb, z, x, use_xb ? xb : (unsigned short*)nullptr, agg, 0);
        zero_kernel<<<(N_NODES + 255) / 256, 256, 0, stream>>>(pos, N_NODES);
        hist_kernel<<<(N_EDGES + 255) / 256, 256, 0, stream>>>(dst, pos);
        scan_partial_kernel<<<SCAN_GRID, SCAN_BLOCK, 0, stream>>>(pos, bsum);
        scan_base_kernel<<<1, 512, 0, stream>>>(bsum);
        scan_final_kernel<<<SCAN_GRID, SCAN_BLOCK, 0, stream>>>(pos, bsum);
        scatter2_kernel<<<(N_EDGES + 255) / 256, 256, 0, stream>>>(dst, src, edge_attr, pos, ssrc, sea);
        if (mfma)
            wprep_kernel<<<((int)WT_ELEMS + 255) / 256, 256, 0, stream>>>(W1, W2, wt);

        for (int l = 0; l < NUM_LAYERS; l++) {
            if (use_xb) {
                gather3_kernel<<<(N_NODES * 32 + 255) / 256, 256, 0, stream>>>(
                    x, xb, ssrc, sea, pos,
                    We + (size_t)l * EDGE_CH * HIDDEN, be + (size_t)l * HIDDEN, agg);
            } else {
                gather2_kernel<<<(N_NODES * 32 + 255) / 256, 256, 0, stream>>>(
                    x, ssrc, sea, pos,
                    We + (size_t)l * EDGE_CH * HIDDEN, be + (size_t)l * HIDDEN, agg);
            }
            if (mfma) {
                mlp_mfma3_kernel<<<MLP3_GRID, 512, 0, stream>>>(
                    agg,
                    wt + (size_t)(l * 2) * HIDDEN * HIDDEN,
                    b1 + (size_t)l * HIDDEN, b2 + (size_t)l * HIDDEN, x,
                    (use_xb && l < NUM_LAYERS - 1) ? xb : (unsigned short*)nullptr);
            } else {
                mlp_kernel<<<MLP_GRID, 256, 0, stream>>>(
                    agg,
                    W1 + (size_t)l * HIDDEN * HIDDEN, b1 + (size_t)l * HIDDEN,
                    W2 + (size_t)l * HIDDEN * HIDDEN, b2 + (size_t)l * HIDDEN, x);
            }
        }
    } else {
        embed_init_kernel<<<(N_NODES * 32) / 256, 256, 0, stream>>>(
            emb, z, x, (unsigned short*)nullptr, agg, 1);
        for (int l = 0; l < NUM_LAYERS; l++) {
            edge_kernel<<<(N_EDGES * 32) / 256, 256, 0, stream>>>(
                x, edge_attr, src, dst,
                We + (size_t)l * EDGE_CH * HIDDEN, be + (size_t)l * HIDDEN, agg);
            mlp_kernel<<<MLP_GRID, 256, 0, stream>>>(
                agg,
                W1 + (size_t)l * HIDDEN * HIDDEN, b1 + (size_t)l * HIDDEN,
                W2 + (size_t)l * HIDDEN * HIDDEN, b2 + (size_t)l * HIDDEN, x);
        }
    }

    batch_out_kernel<<<(N_NODES + 255) / 256, 256, 0, stream>>>(bv, x + (size_t)N_NODES * HIDDEN);
}